// Round 1
// baseline (45.562 us; speedup 1.0000x reference)
//
#include <hip/hip_runtime.h>
#include <math.h>

// DistMul score: out[i] = sigmoid( sum_d ent[h[i]][d] * rel[r[i]][d] * ent[t[i]][d] )
// EMB_DIM = 128 floats = 512 B per row. One 32-lane group per batch element:
// lane g loads float4 at d = g*4 -> 32 lanes x 16 B = 512 B, a single fully
// coalesced segment per row. Shuffle-reduce within the 32-lane group.

#define EMB_DIM 128

__global__ __launch_bounds__(256) void distmul_kernel(
    const int* __restrict__ bh,
    const int* __restrict__ bt,
    const int* __restrict__ br,
    const float* __restrict__ ent,
    const float* __restrict__ rel,
    float* __restrict__ out,
    int batch)
{
    const int g     = threadIdx.x & 31;   // lane within 32-lane group
    const int group = threadIdx.x >> 5;   // group index within block (0..7)
    const int elem  = blockIdx.x * 8 + group;
    if (elem >= batch) return;

    // Indices (wave-uniform per group; scalar cached loads)
    const long long h = bh[elem];
    const long long t = bt[elem];
    const long long r = br[elem];

    const float4 h4 = *reinterpret_cast<const float4*>(ent + h * EMB_DIM + g * 4);
    const float4 t4 = *reinterpret_cast<const float4*>(ent + t * EMB_DIM + g * 4);
    const float4 r4 = *reinterpret_cast<const float4*>(rel + r * EMB_DIM + g * 4);

    float s = h4.x * r4.x * t4.x
            + h4.y * r4.y * t4.y
            + h4.z * r4.z * t4.z
            + h4.w * r4.w * t4.w;

    // Reduce across the 32-lane group (xor masks < 32 stay within the group)
    #pragma unroll
    for (int m = 16; m >= 1; m >>= 1)
        s += __shfl_xor(s, m);

    if (g == 0)
        out[elem] = 1.0f / (1.0f + expf(-s));
}

extern "C" void kernel_launch(void* const* d_in, const int* in_sizes, int n_in,
                              void* d_out, int out_size, void* d_ws, size_t ws_size,
                              hipStream_t stream) {
    const int*   bh  = (const int*)d_in[0];
    const int*   bt  = (const int*)d_in[1];
    const int*   br  = (const int*)d_in[2];
    const float* ent = (const float*)d_in[3];
    const float* rel = (const float*)d_in[4];
    float*       out = (float*)d_out;

    const int batch = in_sizes[0];           // 262144
    const int elems_per_block = 8;           // 256 threads / 32-lane groups
    const int grid = (batch + elems_per_block - 1) / elems_per_block;

    distmul_kernel<<<grid, 256, 0, stream>>>(bh, bt, br, ent, rel, out, batch);
}